// Round 2
// baseline (296.763 us; speedup 1.0000x reference)
//
#include <hip/hip_runtime.h>
#include <hip/hip_fp16.h>
#include <math.h>

typedef __attribute__((ext_vector_type(8))) short bf16x8;
typedef __attribute__((ext_vector_type(4))) float f32x4;

static __device__ __forceinline__ unsigned short f2bf(float x) {
    unsigned u = __float_as_uint(x);
    unsigned r = (u + 0x7FFF + ((u >> 16) & 1)) >> 16;
    return (unsigned short)r;
}
static __device__ __forceinline__ float bf2f(unsigned short h) {
    return __uint_as_float(((unsigned)h) << 16);
}
static __device__ __forceinline__ void addh8(float* a, uint4 v) {
    float2 f;
    f = __half22float2(*(const __half2*)&v.x); a[0] += f.x; a[1] += f.y;
    f = __half22float2(*(const __half2*)&v.y); a[2] += f.x; a[3] += f.y;
    f = __half22float2(*(const __half2*)&v.z); a[4] += f.x; a[5] += f.y;
    f = __half22float2(*(const __half2*)&v.w); a[6] += f.x; a[7] += f.y;
}

// ---------------- CSR build ----------------

__global__ __launch_bounds__(256) void count_deg_kernel(const int* __restrict__ dst, int E,
                                                        int* __restrict__ deg,
                                                        int* __restrict__ epos) {
    int e = blockIdx.x * 256 + threadIdx.x;
    if (e < E) epos[e] = atomicAdd(&deg[dst[e]], 1);
}

__global__ __launch_bounds__(256) void scan_partial_kernel(const int* __restrict__ deg, int n,
                                                           int* __restrict__ partials) {
    int idx = blockIdx.x * 1024 + threadIdx.x * 4;
    int4 v = make_int4(0, 0, 0, 0);
    if (idx + 3 < n) v = *(const int4*)(deg + idx);
    else {
        if (idx < n) v.x = deg[idx];
        if (idx + 1 < n) v.y = deg[idx + 1];
        if (idx + 2 < n) v.z = deg[idx + 2];
    }
    int s = v.x + v.y + v.z + v.w;
    for (int off = 1; off < 64; off <<= 1) s += __shfl_xor(s, off);
    __shared__ int sm[4];
    int wave = threadIdx.x >> 6;
    if ((threadIdx.x & 63) == 0) sm[wave] = s;
    __syncthreads();
    if (threadIdx.x == 0) partials[blockIdx.x] = sm[0] + sm[1] + sm[2] + sm[3];
}

__global__ __launch_bounds__(256) void scan_final_kernel(const int* __restrict__ deg, int n,
                                                         const int* __restrict__ partials, int nbk,
                                                         int* __restrict__ rowptr) {
    int idx = blockIdx.x * 1024 + threadIdx.x * 4;
    int4 v = make_int4(0, 0, 0, 0);
    if (idx + 3 < n) v = *(const int4*)(deg + idx);
    else {
        if (idx < n) v.x = deg[idx];
        if (idx + 1 < n) v.y = deg[idx + 1];
        if (idx + 2 < n) v.z = deg[idx + 2];
    }
    int tsum = v.x + v.y + v.z + v.w;
    int lane = threadIdx.x & 63, wave = threadIdx.x >> 6;
    int s = tsum;
    for (int off = 1; off < 64; off <<= 1) {
        int u = __shfl_up(s, off);
        if (lane >= off) s += u;
    }
    __shared__ int wsum[4];
    __shared__ int bb;
    if (lane == 63) wsum[wave] = s;
    if (threadIdx.x < 64) {
        int pv = (threadIdx.x < nbk) ? partials[threadIdx.x] : 0;
        int ps = pv;
        for (int off = 1; off < 64; off <<= 1) {
            int u = __shfl_up(ps, off);
            if (threadIdx.x >= off) ps += u;
        }
        if (threadIdx.x == blockIdx.x) bb = ps - pv;
        if (blockIdx.x == 0 && threadIdx.x == 63) rowptr[n] = ps;
    }
    __syncthreads();
    int base = bb;
    for (int w = 0; w < wave; ++w) base += wsum[w];
    int e0 = base + s - tsum;
    int4 o;
    o.x = e0; o.y = e0 + v.x; o.z = o.y + v.y; o.w = o.z + v.z;
    if (idx + 3 < n) *(int4*)(rowptr + idx) = o;
    else {
        if (idx < n) rowptr[idx] = o.x;
        if (idx + 1 < n) rowptr[idx + 1] = o.y;
        if (idx + 2 < n) rowptr[idx + 2] = o.z;
    }
}

// ------- fused prep: scatter | dinv+prescale | W convert (plain [col][k] bf16 split) -------

__global__ __launch_bounds__(256) void prep_kernel(
    const int* __restrict__ src, const int* __restrict__ dst, const int* __restrict__ epos, int E,
    const int* __restrict__ rowptr, int* __restrict__ csrsrc, int scatterBlocks,
    const float* __restrict__ x, float* __restrict__ dinv,
    __half2* __restrict__ xs16, int n, int prescaleBlocks,
    const float* __restrict__ W1, const float* __restrict__ W2,
    unsigned short* __restrict__ w1h, unsigned short* __restrict__ w1l,
    unsigned short* __restrict__ w2h, unsigned short* __restrict__ w2l) {
    int b = blockIdx.x;
    if (b < scatterBlocks) {
        int e = b * 256 + threadIdx.x;
        if (e < E) csrsrc[rowptr[dst[e]] + epos[e]] = src[e];
    } else if (b < scatterBlocks + prescaleBlocks) {
        int node = (b - scatterBlocks) * 4 + (threadIdx.x >> 6);
        int lane = threadIdx.x & 63;
        if (node >= n) return;
        float di = rsqrtf((float)(rowptr[node + 1] - rowptr[node] + 1));
        if (lane == 0) dinv[node] = di;
        float2 v = *(const float2*)(x + (size_t)node * 128 + (lane << 1));
        xs16[(size_t)node * 64 + lane] = __floats2half2_rn(di * v.x, di * v.y);
    } else {
        int i = (b - scatterBlocks - prescaleBlocks) * 256 + threadIdx.x;
        if (i < 128 * 128) {
            int nn = i >> 7, k = i & 127;
            float v = W1[k * 128 + nn];
            unsigned short h = f2bf(v);
            w1h[nn * 128 + k] = h;
            w1l[nn * 128 + k] = f2bf(v - bf2f(h));
        } else if (i < 128 * 128 + 256 * 128) {
            int j = i - 128 * 128;
            int nn = j >> 7, k = j & 127;
            float v = W2[k * 256 + nn];
            unsigned short h = f2bf(v);
            w2h[nn * 128 + k] = h;
            w2l[nn * 128 + k] = f2bf(v - bf2f(h));
        }
    }
}

// ---------------- fused aggregate + split-bf16 MFMA GEMM ----------------
// One block = 128 output rows, all NCOLS columns. Gather phase: 4 threads/node
// accumulate fp32 neighbor sums from fp16 rows, split to bf16 H/L directly into
// swizzled LDS. MFMA phase: A-frags from LDS (conflict-free XOR granule layout),
// B-frags straight from global (weights are L1/L2-resident). Single barrier.

template <int NCOLS, bool SCALE_DINV, bool DO_LOGITS, bool OUT_F16>
__global__ __launch_bounds__(512, 2) void fused_gemm(
    const unsigned short* __restrict__ X16,
    const int* __restrict__ rowptr, const int* __restrict__ csrsrc,
    const float* __restrict__ dinv,
    const unsigned short* __restrict__ Bth, const unsigned short* __restrict__ Btl,
    const float* __restrict__ bias, void* __restrict__ Cout, int M,
    const float* __restrict__ Wa, float* __restrict__ logits) {
    constexpr int CT = NCOLS / 64;   // col-tiles per wave (4 waves across columns)
    __shared__ unsigned short AsH[128 * 128];
    __shared__ unsigned short AsL[128 * 128];

    const int t = threadIdx.x;
    const int row0 = blockIdx.x * 128;

    // ---------- gather phase ----------
    {
        const int nl = t >> 2;        // local node 0..127
        const int sub = t & 3;        // feature quarter: k in [sub*32, sub*32+32)
        const int row = row0 + nl;
        float acc[32];
#pragma unroll
        for (int i = 0; i < 32; ++i) acc[i] = 0.f;
        float di = 0.f;
        if (row < M) {
            const uint4* __restrict__ Xv = (const uint4*)X16;
            size_t sb = (size_t)row * 16 + sub * 4;
            uint4 v0 = Xv[sb], v1 = Xv[sb + 1], v2 = Xv[sb + 2], v3 = Xv[sb + 3];
            addh8(acc, v0); addh8(acc + 8, v1); addh8(acc + 16, v2); addh8(acc + 24, v3);
            int e1 = rowptr[row + 1];
            int e = rowptr[row];
            for (; e + 2 <= e1; e += 2) {
                int s0 = csrsrc[e], s1 = csrsrc[e + 1];
                size_t b0 = (size_t)s0 * 16 + sub * 4;
                size_t b1 = (size_t)s1 * 16 + sub * 4;
                uint4 a0 = Xv[b0], a1 = Xv[b0 + 1], a2 = Xv[b0 + 2], a3 = Xv[b0 + 3];
                uint4 c0 = Xv[b1], c1 = Xv[b1 + 1], c2 = Xv[b1 + 2], c3 = Xv[b1 + 3];
                addh8(acc, a0); addh8(acc + 8, a1); addh8(acc + 16, a2); addh8(acc + 24, a3);
                addh8(acc, c0); addh8(acc + 8, c1); addh8(acc + 16, c2); addh8(acc + 24, c3);
            }
            if (e < e1) {
                size_t b0 = (size_t)csrsrc[e] * 16 + sub * 4;
                uint4 a0 = Xv[b0], a1 = Xv[b0 + 1], a2 = Xv[b0 + 2], a3 = Xv[b0 + 3];
                addh8(acc, a0); addh8(acc + 8, a1); addh8(acc + 16, a2); addh8(acc + 24, a3);
            }
            di = dinv[row];
        }
        // split to bf16 H/L and write swizzled LDS (rows >= M write zeros: di==0)
#pragma unroll
        for (int j = 0; j < 4; ++j) {
            int ga = sub * 4 + j;                                     // absolute granule 0..15
            int off = nl * 128 + (ga >> 3) * 64 + (((ga & 7) ^ (nl & 7)) << 3);
            unsigned short h[8], l[8];
#pragma unroll
            for (int q = 0; q < 8; ++q) {
                float f = di * acc[j * 8 + q];
                h[q] = f2bf(f);
                l[q] = f2bf(f - bf2f(h[q]));
            }
            uint4 hv, lv;
            hv.x = (unsigned)h[0] | ((unsigned)h[1] << 16);
            hv.y = (unsigned)h[2] | ((unsigned)h[3] << 16);
            hv.z = (unsigned)h[4] | ((unsigned)h[5] << 16);
            hv.w = (unsigned)h[6] | ((unsigned)h[7] << 16);
            lv.x = (unsigned)l[0] | ((unsigned)l[1] << 16);
            lv.y = (unsigned)l[2] | ((unsigned)l[3] << 16);
            lv.z = (unsigned)l[4] | ((unsigned)l[5] << 16);
            lv.w = (unsigned)l[6] | ((unsigned)l[7] << 16);
            *(uint4*)(AsH + off) = hv;
            *(uint4*)(AsL + off) = lv;
        }
    }
    __syncthreads();

    // ---------- MFMA phase ----------
    const int lane = t & 63;
    const int wave = t >> 6;       // 0..7
    const int wrow = wave >> 2;    // 0..1  (64 rows each)
    const int wcol = wave & 3;     // 0..3  (16*CT cols each)
    const int lq = lane >> 4;
    const int lm = lane & 15;

    f32x4 acc2[4][CT] = {};
    float lacc[4][4] = {};

#pragma unroll
    for (int kc = 0; kc < 2; ++kc)
#pragma unroll
        for (int ks = 0; ks < 2; ++ks) {
            const int gbase = ks * 4 + lq;
            bf16x8 ah[4], al[4], bh[CT], bl[CT];
#pragma unroll
            for (int rt = 0; rt < 4; ++rt) {
                int ra = wrow * 64 + rt * 16 + lm;
                int off = ra * 128 + kc * 64 + ((gbase ^ (ra & 7)) << 3);
                ah[rt] = *(const bf16x8*)(AsH + off);
                al[rt] = *(const bf16x8*)(AsL + off);
            }
#pragma unroll
            for (int ct = 0; ct < CT; ++ct) {
                int col = wcol * (16 * CT) + ct * 16 + lm;
                size_t bo = (size_t)col * 128 + kc * 64 + gbase * 8;
                bh[ct] = *(const bf16x8*)(Bth + bo);
                bl[ct] = *(const bf16x8*)(Btl + bo);
            }
#pragma unroll
            for (int rt = 0; rt < 4; ++rt)
#pragma unroll
                for (int ct = 0; ct < CT; ++ct) {
                    acc2[rt][ct] = __builtin_amdgcn_mfma_f32_16x16x32_bf16(ah[rt], bh[ct], acc2[rt][ct], 0, 0, 0);
                    acc2[rt][ct] = __builtin_amdgcn_mfma_f32_16x16x32_bf16(al[rt], bh[ct], acc2[rt][ct], 0, 0, 0);
                    acc2[rt][ct] = __builtin_amdgcn_mfma_f32_16x16x32_bf16(ah[rt], bl[ct], acc2[rt][ct], 0, 0, 0);
                }
        }

    // epilogue: C/D frag layout col = lm, row = lq*4 + reg
#pragma unroll
    for (int ct = 0; ct < CT; ++ct) {
        int col = wcol * (16 * CT) + ct * 16 + lm;
        float bc = bias[col];
        float wac = DO_LOGITS ? Wa[col] : 0.f;
#pragma unroll
        for (int rt = 0; rt < 4; ++rt) {
            int rowb = row0 + wrow * 64 + rt * 16 + lq * 4;
#pragma unroll
            for (int reg = 0; reg < 4; ++reg) {
                int gr = rowb + reg;
                if (gr < M) {
                    float o = fmaxf(acc2[rt][ct][reg] + bc, 0.f);
                    if (SCALE_DINV) o *= dinv[gr];
                    if (OUT_F16) ((__half*)Cout)[(size_t)gr * NCOLS + col] = __float2half(o);
                    else ((float*)Cout)[(size_t)gr * NCOLS + col] = o;
                    if (DO_LOGITS) lacc[rt][reg] += o * wac;
                }
            }
        }
    }

    if (DO_LOGITS) {
#pragma unroll
        for (int rt = 0; rt < 4; ++rt)
#pragma unroll
            for (int reg = 0; reg < 4; ++reg) {
                float s = lacc[rt][reg];
                s += __shfl_xor(s, 1);
                s += __shfl_xor(s, 2);
                s += __shfl_xor(s, 4);
                s += __shfl_xor(s, 8);
                int gr = row0 + wrow * 64 + rt * 16 + lq * 4 + reg;
                if (lm == 0 && gr < M) atomicAdd(&logits[gr], s);
            }
    }
}

// ---------------- attention pooling ----------------

__global__ __launch_bounds__(256) void maxsum_kernel(const float* __restrict__ logits, int n,
                                                     float2* __restrict__ part,
                                                     float* __restrict__ outTail) {
    if (blockIdx.x == 0) outTail[threadIdx.x] = 0.f;
    float m = -INFINITY, s = 0.f;
    for (int i = blockIdx.x * 256 + threadIdx.x; i < n; i += gridDim.x * 256) {
        float v = logits[i];
        if (v > m) { s = s * expf(m - v) + 1.f; m = v; }
        else s += expf(v - m);
    }
    __shared__ float sm[256], ss[256];
    sm[threadIdx.x] = m; ss[threadIdx.x] = s;
    __syncthreads();
    for (int off = 128; off > 0; off >>= 1) {
        if (threadIdx.x < off) {
            float m1 = sm[threadIdx.x], s1 = ss[threadIdx.x];
            float m2 = sm[threadIdx.x + off], s2 = ss[threadIdx.x + off];
            float M = fmaxf(m1, m2);
            sm[threadIdx.x] = M;
            ss[threadIdx.x] = s1 * expf(m1 - M) + s2 * expf(m2 - M);
        }
        __syncthreads();
    }
    if (threadIdx.x == 0) part[blockIdx.x] = make_float2(sm[0], ss[0]);
}

static __device__ __forceinline__ float2 merge_part(const float2* __restrict__ part, int t,
                                                    float* red2) {
    if (t < 64) {
        float2 p = part[t];
        float m = p.x, s = p.y;
        for (int off = 32; off > 0; off >>= 1) {
            float m2 = __shfl_xor(m, off);
            float s2 = __shfl_xor(s, off);
            float M = fmaxf(m, m2);
            s = s * expf(m - M) + s2 * expf(m2 - M);
            m = M;
        }
        if (t == 0) { red2[0] = m; red2[1] = s; }
    }
    __syncthreads();
    return make_float2(red2[0], red2[1]);
}

__global__ __launch_bounds__(256) void weighted_sum_kernel(const float* __restrict__ emb,
                                                           const float* __restrict__ logits,
                                                           const float2* __restrict__ part,
                                                           float* __restrict__ gpart, int n) {
    __shared__ float red2[2];
    float g = merge_part(part, threadIdx.x, red2).x;
    int wave = threadIdx.x >> 6;
    int lane = threadIdx.x & 63;
    int stride = gridDim.x * 4;
    float4 acc = make_float4(0.f, 0.f, 0.f, 0.f);
#pragma unroll 2
    for (int r = blockIdx.x * 4 + wave; r < n; r += stride) {
        float w = expf(logits[r] - g);
        float4 v = *(const float4*)(emb + (size_t)r * 256 + (lane << 2));
        acc.x += w * v.x; acc.y += w * v.y; acc.z += w * v.z; acc.w += w * v.w;
    }
    __shared__ float4 sm[256];
    sm[threadIdx.x] = acc;
    __syncthreads();
    if (wave == 0) {
        float4 a = sm[lane], b = sm[64 + lane], c = sm[128 + lane], d = sm[192 + lane];
        float4 s;
        s.x = (a.x + b.x) + (c.x + d.x);
        s.y = (a.y + b.y) + (c.y + d.y);
        s.z = (a.z + b.z) + (c.z + d.z);
        s.w = (a.w + b.w) + (c.w + d.w);
        *(float4*)(gpart + (size_t)blockIdx.x * 256 + (lane << 2)) = s;
    }
}

__global__ __launch_bounds__(256) void reduce_gpart_kernel(const float* __restrict__ gpart,
                                                           const float2* __restrict__ part,
                                                           float* __restrict__ outTail, int nb) {
    __shared__ float red2[2];
    float gsum = merge_part(part, threadIdx.x, red2).y;
    int rows = nb / gridDim.x;
    int r0 = blockIdx.x * rows;
    float s = 0.f;
    for (int r = r0; r < r0 + rows; ++r) s += gpart[(size_t)r * 256 + threadIdx.x];
    atomicAdd(&outTail[threadIdx.x], s / gsum);
}

// ---------------- launch ----------------

extern "C" void kernel_launch(void* const* d_in, const int* in_sizes, int n_in,
                              void* d_out, int out_size, void* d_ws, size_t ws_size,
                              hipStream_t stream) {
    const float* x  = (const float*)d_in[0];
    const int* ei   = (const int*)d_in[1];
    const float* W1 = (const float*)d_in[2];
    const float* b1 = (const float*)d_in[3];
    const float* W2 = (const float*)d_in[4];
    const float* b2 = (const float*)d_in[5];
    const float* Wa = (const float*)d_in[6];
    float* out = (float*)d_out;

    const int n = in_sizes[0] / 128;  // 50000
    const int E = in_sizes[1] / 2;    // 800000
    const int* srcA = ei;
    const int* dstA = ei + E;
    const int nb = (n + 1023) / 1024;
    const int WS_BLOCKS = 1024;

    // workspace layout (logits and deg adjacent -> single memset)
    unsigned short* xs16 = (unsigned short*)d_ws;         // n*128 fp16 (prescaled X)
    unsigned short* h16  = xs16 + (size_t)n * 128;        // n*128 fp16 (prescaled h)
    unsigned short* w1h  = h16 + (size_t)n * 128;         // 128 cols * 128 k
    unsigned short* w1l  = w1h + 128 * 128;
    unsigned short* w2h  = w1l + 128 * 128;               // 256 cols * 128 k
    unsigned short* w2l  = w2h + 256 * 128;
    float* dinv   = (float*)(w2l + 256 * 128);            // n
    float* logits = dinv + n;                             // n   (zeroed)
    int* deg      = (int*)(logits + n);                   // n   (zeroed, adjacent)
    int* rowptr   = deg + n;                              // n+1
    int* partials = rowptr + n + 1;                       // 64
    float2* part  = (float2*)(partials + 64);             // 64
    float* gpart  = (float*)(part + 64);                  // WS_BLOCKS*256
    int* epos     = (int*)(gpart + WS_BLOCKS * 256);      // E
    int* csrsrc   = epos + E;                             // E

    hipMemsetAsync(logits, 0, sizeof(float) * (size_t)(2 * n), stream);  // logits + deg

    count_deg_kernel<<<(E + 255) / 256, 256, 0, stream>>>(dstA, E, deg, epos);
    scan_partial_kernel<<<nb, 256, 0, stream>>>(deg, n, partials);
    scan_final_kernel<<<nb, 256, 0, stream>>>(deg, n, partials, nb, rowptr);

    int scatterBlocks = (E + 255) / 256;
    int prescaleBlocks = (n + 3) / 4;
    int wconvBlocks = (128 * 128 + 256 * 128 + 255) / 256;
    prep_kernel<<<scatterBlocks + prescaleBlocks + wconvBlocks, 256, 0, stream>>>(
        srcA, dstA, epos, E, rowptr, csrsrc, scatterBlocks,
        x, dinv, (__half2*)xs16, n, prescaleBlocks,
        W1, W2, w1h, w1l, w2h, w2l);

    int gemmRows = (n + 127) / 128;

    fused_gemm<128, true, false, true><<<gemmRows, 512, 0, stream>>>(
        xs16, rowptr, csrsrc, dinv, w1h, w1l, b1, h16, n, nullptr, nullptr);
    fused_gemm<256, false, true, false><<<gemmRows, 512, 0, stream>>>(
        h16, rowptr, csrsrc, dinv, w2h, w2l, b2, out, n, Wa, logits);

    maxsum_kernel<<<64, 256, 0, stream>>>(logits, n, part, out + (size_t)n * 256);
    weighted_sum_kernel<<<WS_BLOCKS, 256, 0, stream>>>(out, logits, part, gpart, n);
    reduce_gpart_kernel<<<32, 256, 0, stream>>>(gpart, part, out + (size_t)n * 256, WS_BLOCKS);
}